// Round 14
// baseline (1259.689 us; speedup 1.0000x reference)
//
#include <hip/hip_runtime.h>
#include <cstdint>
#include <cstddef>

// ---------------------------------------------------------------------------
// SplitLayer. Round 11 (resubmit after broker timeout): round-6 GEMM kernels
// (best measured) + round-10 aliasing (neutral, kept) + gather1 FUSED into
// the cat GEMM. gather1 only materialized `lift` (102MB write) for cat to
// re-read (102MB); node_rep is 25.6MB = L3-resident, so doing the segment-sum
// inside cat's loadRegs trades the HBM round-trip for L3 hits and kills one
// kernel launch.
// ---------------------------------------------------------------------------

typedef __bf16 bf16_t;
typedef __bf16 bf16x4 __attribute__((ext_vector_type(4)));
typedef __bf16 bf16x8 __attribute__((ext_vector_type(8)));
typedef float f32x4 __attribute__((ext_vector_type(4)));

__device__ __forceinline__ void atomAddF(float* p, float v) {
  unsafeAtomicAdd(p, v);
}

__device__ __forceinline__ void gload16(const void* g, void* l) {
  __builtin_amdgcn_global_load_lds(
      (const __attribute__((address_space(1))) unsigned int*)g,
      (__attribute__((address_space(3))) unsigned int*)l, 16, 0, 0);
}

// ============================ CSR construction ==============================

__global__ __launch_bounds__(256) void k_hist(
    const int* __restrict__ src, const int* __restrict__ dst, int M,
    int* __restrict__ cnt_e, int* __restrict__ cnt_n) {
  int i = blockIdx.x * blockDim.x + threadIdx.x;
  if (i >= M) return;
  atomicAdd(cnt_e + dst[i], 1);
  atomicAdd(cnt_n + src[i], 1);
}

__global__ __launch_bounds__(256) void k_scan_block(
    const int* __restrict__ in, int* __restrict__ out, int* __restrict__ bsum,
    int L) {
  __shared__ int sh[256];
  int t = threadIdx.x;
  int base = (blockIdx.x * 256 + t) * 4;
  int v[4];
#pragma unroll
  for (int j = 0; j < 4; ++j) v[j] = (base + j < L) ? in[base + j] : 0;
  int tsum = v[0] + v[1] + v[2] + v[3];
  sh[t] = tsum;
  __syncthreads();
#pragma unroll
  for (int off = 1; off < 256; off <<= 1) {
    int x = (t >= off) ? sh[t - off] : 0;
    __syncthreads();
    sh[t] += x;
    __syncthreads();
  }
  int excl = sh[t] - tsum;
  if (t == 255) bsum[blockIdx.x] = sh[255];
  int run = excl;
#pragma unroll
  for (int j = 0; j < 4; ++j) {
    if (base + j < L) out[base + j] = run;
    run += v[j];
  }
}

__global__ __launch_bounds__(1024) void k_scan_top(int* __restrict__ bsum,
                                                   int nb) {
  __shared__ int sh[1024];
  __shared__ int running;
  int t = threadIdx.x;
  if (t == 0) running = 0;
  __syncthreads();
  for (int c = 0; c < nb; c += 1024) {
    int i = c + t;
    int v = (i < nb) ? bsum[i] : 0;
    sh[t] = v;
    __syncthreads();
#pragma unroll
    for (int off = 1; off < 1024; off <<= 1) {
      int x = (t >= off) ? sh[t - off] : 0;
      __syncthreads();
      sh[t] += x;
      __syncthreads();
    }
    int r = running;
    if (i < nb) bsum[i] = r + sh[t] - v;
    __syncthreads();
    if (t == 1023) running = r + sh[1023];
    __syncthreads();
  }
}

__global__ __launch_bounds__(256) void k_scan_add(int* __restrict__ out,
                                                  const int* __restrict__ bsum,
                                                  int L) {
  int base = (blockIdx.x * 256 + threadIdx.x) * 4;
  int add = bsum[blockIdx.x];
#pragma unroll
  for (int j = 0; j < 4; ++j)
    if (base + j < L) out[base + j] += add;
}

__global__ void k_settail(int* off_e, int E, int* off_n, int N, int M) {
  off_e[E] = M;
  off_n[N] = M;
}

__global__ __launch_bounds__(256) void k_fill(
    const int* __restrict__ src, const int* __restrict__ dst, int M,
    const int* __restrict__ off_e, int* __restrict__ fill_e,
    int* __restrict__ csr_e, const int* __restrict__ off_n,
    int* __restrict__ fill_n, int* __restrict__ csr_n) {
  int i = blockIdx.x * blockDim.x + threadIdx.x;
  if (i >= M) return;
  int s = src[i], d = dst[i];
  int pe = off_e[d] + atomicAdd(fill_e + d, 1);
  csr_e[pe] = s;
  int pn = off_n[s] + atomicAdd(fill_n + s, 1);
  csr_n[pn] = d;
}

// ============================ weight transpose+convert ======================
__global__ __launch_bounds__(256) void k_wconv(const float* __restrict__ W,
                                               bf16_t* __restrict__ Wt, int K,
                                               int NC) {
  int idx = blockIdx.x * blockDim.x + threadIdx.x;
  if (idx >= K * NC) return;
  int k = idx / NC, n = idx % NC;
  Wt[(size_t)n * K + k] = (bf16_t)W[idx];
}

// ============================ gather2: lvl + hn =============================
__global__ __launch_bounds__(256) void k_gather2(
    const bf16_t* __restrict__ Y1, const float* __restrict__ st,
    const float* __restrict__ node, const int* __restrict__ off_n,
    const int* __restrict__ csr_n, const float* __restrict__ eps1p,
    bf16_t* __restrict__ hn, int N) {
  int n = blockIdx.x * 16 + (threadIdx.x >> 4);
  if (n >= N) return;
  int l = threadIdx.x & 15;
  float a1 = 1.0f + eps1p[0];
  float4 s0 = *(const float4*)(st + l * 8);
  float4 s1 = *(const float4*)(st + l * 8 + 4);
  float4 t0 = *(const float4*)(st + 128 + l * 8);
  float4 t1 = *(const float4*)(st + 128 + l * 8 + 4);
  float acc[8] = {0.f, 0.f, 0.f, 0.f, 0.f, 0.f, 0.f, 0.f};
  int b = off_n[n], en = off_n[n + 1];
  for (int j = b; j < en; ++j) {
    int r = csr_n[j];
    bf16x8 y = *(const bf16x8*)(Y1 + (size_t)r * 128 + l * 8);
    acc[0] += fmaxf(fmaf((float)y[0], s0.x, t0.x), 0.f);
    acc[1] += fmaxf(fmaf((float)y[1], s0.y, t0.y), 0.f);
    acc[2] += fmaxf(fmaf((float)y[2], s0.z, t0.z), 0.f);
    acc[3] += fmaxf(fmaf((float)y[3], s0.w, t0.w), 0.f);
    acc[4] += fmaxf(fmaf((float)y[4], s1.x, t1.x), 0.f);
    acc[5] += fmaxf(fmaf((float)y[5], s1.y, t1.y), 0.f);
    acc[6] += fmaxf(fmaf((float)y[6], s1.z, t1.z), 0.f);
    acc[7] += fmaxf(fmaf((float)y[7], s1.w, t1.w), 0.f);
  }
  float4 n0 = *(const float4*)(node + (size_t)n * 128 + l * 8);
  float4 n1 = *(const float4*)(node + (size_t)n * 128 + l * 8 + 4);
  bf16x8 hb;
  hb[0] = (bf16_t)fmaf(a1, n0.x, acc[0]);
  hb[1] = (bf16_t)fmaf(a1, n0.y, acc[1]);
  hb[2] = (bf16_t)fmaf(a1, n0.z, acc[2]);
  hb[3] = (bf16_t)fmaf(a1, n0.w, acc[3]);
  hb[4] = (bf16_t)fmaf(a1, n1.x, acc[4]);
  hb[5] = (bf16_t)fmaf(a1, n1.y, acc[5]);
  hb[6] = (bf16_t)fmaf(a1, n1.z, acc[6]);
  hb[7] = (bf16_t)fmaf(a1, n1.w, acc[7]);
  *(bf16x8*)(hn + (size_t)n * 128 + l * 8) = hb;
}

// ============================ BN finalize / output ==========================

__global__ void k_bnfin(const float* __restrict__ sums, int C, int R,
                        const float* __restrict__ g, const float* __restrict__ b,
                        float* __restrict__ st) {
  int c = blockIdx.x * blockDim.x + threadIdx.x;
  if (c >= C) return;
  float invR = 1.f / (float)R;
  float mean = sums[c] * invR;
  float var = fmaxf(sums[C + c] * invR - mean * mean, 0.f);
  float s = g[c] * rsqrtf(var + 1e-5f);
  st[c] = s;
  st[C + c] = fmaf(-mean, s, b[c]);
}

__global__ __launch_bounds__(256) void k_bnrelu_out(
    const bf16_t* __restrict__ Y, const float* __restrict__ st, long R,
    float* __restrict__ out) {
  long t = (long)blockIdx.x * blockDim.x + threadIdx.x;
  long idx = t * 8;
  if (idx >= R * 128) return;
  int c = (int)(idx & 127);
  bf16x8 y = *(const bf16x8*)(Y + idx);
  float4 s0 = *(const float4*)(st + c);
  float4 s1 = *(const float4*)(st + c + 4);
  float4 t0 = *(const float4*)(st + 128 + c);
  float4 t1 = *(const float4*)(st + 128 + c + 4);
  float4 o0, o1;
  o0.x = fmaxf(fmaf((float)y[0], s0.x, t0.x), 0.f);
  o0.y = fmaxf(fmaf((float)y[1], s0.y, t0.y), 0.f);
  o0.z = fmaxf(fmaf((float)y[2], s0.z, t0.z), 0.f);
  o0.w = fmaxf(fmaf((float)y[3], s0.w, t0.w), 0.f);
  o1.x = fmaxf(fmaf((float)y[4], s1.x, t1.x), 0.f);
  o1.y = fmaxf(fmaf((float)y[5], s1.y, t1.y), 0.f);
  o1.z = fmaxf(fmaf((float)y[6], s1.z, t1.z), 0.f);
  o1.w = fmaxf(fmaf((float)y[7], s1.w, t1.w), 0.f);
  *(float4*)(out + idx) = o0;
  *(float4*)(out + idx + 4) = o1;
}

// =================== reg-resident-B, LDS-streamed-A GEMM ====================
// (round-6 version verbatim)
template <int K, int NC, int TRANSFORM>
__global__ __launch_bounds__(256, 2) void k_gemm_rb(
    const bf16_t* __restrict__ A, const bf16_t* __restrict__ Wt,
    const float* __restrict__ st, float* __restrict__ gstats,
    bf16_t* __restrict__ Y, int R) {
  constexpr int K2 = K * 2;
  constexpr int KF = K / 32;
  constexpr int CTW = NC / 64;
  constexpr int STG = K2 / 64;
  constexpr int TILEB = 64 * K2;
  __shared__ __align__(16) char ldsc[65536];
  const int tid = threadIdx.x;

  for (int p = tid * 16; p < 65536; p += 4096)
    *(float4*)(ldsc + p) = *(const float4*)((const char*)Wt + p);
  __syncthreads();
  const int wv = tid >> 6, lane = tid & 63, quad = lane >> 4, l16 = lane & 15;
  bf16x8 breg[CTW][KF];
#pragma unroll
  for (int ct = 0; ct < CTW; ++ct) {
    const int col = wv * (NC / 4) + ct * 16 + l16;
#pragma unroll
    for (int f = 0; f < KF; ++f)
      breg[ct][f] = *(const bf16x8*)(ldsc + col * K2 + f * 64 + quad * 16);
  }
  __syncthreads();

  int stg_off[STG], stg_row[STG];
#pragma unroll
  for (int j = 0; j < STG; ++j) {
    const int p = j * 1024 + lane * 16;
    const int rl = p / K2;
    const int cg = ((p & (K2 - 1)) >> 4) ^ (rl & 7);
    stg_row[j] = rl;
    stg_off[j] = rl * K2 + cg * 16;
  }
  const int ntiles = (R + 63) >> 6;
  auto stage = [&](int t, int b) {
    char* db = ldsc + b * TILEB + wv * (16 * K2);
    if (t * 64 + 64 <= R) {
      const char* srcb = (const char*)A + (size_t)(t * 64 + wv * 16) * K2;
#pragma unroll
      for (int j = 0; j < STG; ++j) gload16(srcb + stg_off[j], db + j * 1024);
    } else {
#pragma unroll
      for (int j = 0; j < STG; ++j) {
        int g = t * 64 + wv * 16 + stg_row[j];
        if (g > R - 1) g = R - 1;
        gload16((const char*)A + (size_t)g * K2 +
                    (stg_off[j] - stg_row[j] * K2),
                db + j * 1024);
      }
    }
  };

  float csum[CTW], csq[CTW];
#pragma unroll
  for (int ct = 0; ct < CTW; ++ct) { csum[ct] = 0.f; csq[ct] = 0.f; }

  int t = blockIdx.x, b = 0;
  if (t < ntiles) stage(t, 0);
  __syncthreads();
  for (; t < ntiles; t += gridDim.x) {
    const int tn = t + gridDim.x;
    if (tn < ntiles) stage(tn, b ^ 1);
    const char* Ab = ldsc + b * TILEB;
    f32x4 acc[4][CTW] = {};
#pragma unroll
    for (int f = 0; f < KF; ++f) {
      const int csw = ((f * 4 + quad) ^ (l16 & 7)) * 16;
      float4 s0, s1, u0, u1;
      if constexpr (TRANSFORM != 0) {
        const int k = f * 32 + quad * 8;
        s0 = *(const float4*)(st + k);
        s1 = *(const float4*)(st + k + 4);
        u0 = *(const float4*)(st + K + k);
        u1 = *(const float4*)(st + K + k + 4);
      }
#pragma unroll
      for (int rg = 0; rg < 4; ++rg) {
        bf16x8 a = *(const bf16x8*)(Ab + (rg * 16 + l16) * K2 + csw);
        if constexpr (TRANSFORM != 0) {
          bf16x8 o;
          o[0] = (bf16_t)fmaxf(fmaf((float)a[0], s0.x, u0.x), 0.f);
          o[1] = (bf16_t)fmaxf(fmaf((float)a[1], s0.y, u0.y), 0.f);
          o[2] = (bf16_t)fmaxf(fmaf((float)a[2], s0.z, u0.z), 0.f);
          o[3] = (bf16_t)fmaxf(fmaf((float)a[3], s0.w, u0.w), 0.f);
          o[4] = (bf16_t)fmaxf(fmaf((float)a[4], s1.x, u1.x), 0.f);
          o[5] = (bf16_t)fmaxf(fmaf((float)a[5], s1.y, u1.y), 0.f);
          o[6] = (bf16_t)fmaxf(fmaf((float)a[6], s1.z, u1.z), 0.f);
          o[7] = (bf16_t)fmaxf(fmaf((float)a[7], s1.w, u1.w), 0.f);
          a = o;
        }
#pragma unroll
        for (int ct = 0; ct < CTW; ++ct)
          acc[rg][ct] = __builtin_amdgcn_mfma_f32_16x16x32_bf16(
              a, breg[ct][f], acc[rg][ct], 0, 0, 0);
      }
    }
#pragma unroll
    for (int rg = 0; rg < 4; ++rg) {
      const int rowb = t * 64 + rg * 16 + quad * 4;
#pragma unroll
      for (int ct = 0; ct < CTW; ++ct) {
        const int col = wv * (NC / 4) + ct * 16 + l16;
#pragma unroll
        for (int r = 0; r < 4; ++r) {
          const int row = rowb + r;
          if (row < R) {
            const float v = acc[rg][ct][r];
            Y[(size_t)row * NC + col] = (bf16_t)v;
            csum[ct] += v;
            csq[ct] += v * v;
          }
        }
      }
    }
    __syncthreads();
    b ^= 1;
  }
#pragma unroll
  for (int ct = 0; ct < CTW; ++ct) {
    float s = csum[ct], q = csq[ct];
    s += __shfl_xor(s, 16, 64);
    s += __shfl_xor(s, 32, 64);
    q += __shfl_xor(q, 16, 64);
    q += __shfl_xor(q, 32, 64);
    if (quad == 0) {
      const int col = wv * (NC / 4) + ct * 16 + l16;
      atomAddF(gstats + col, s);
      atomAddF(gstats + NC + col, q);
    }
  }
}

// ====== fused concat GEMM-1: gather(node)+[lift|edge]@Wa, emits he ==========
// lift is computed IN-REGISTER via CSR segment-sum over node_rep (L3-resident
// 25.6MB) -- no lift buffer round-trip, no separate gather1 kernel.
__global__ __launch_bounds__(256, 2) void k_gemm_cat_rb(
    const float* __restrict__ node, const int* __restrict__ off_e,
    const int* __restrict__ csr_e, const float* __restrict__ edge,
    const bf16_t* __restrict__ Wt, const float* __restrict__ eps2p,
    float* __restrict__ gstats, bf16_t* __restrict__ Y,
    bf16_t* __restrict__ he, int R) {
  constexpr int KF = 8, CTW = 2;
  __shared__ __align__(16) char ldsc[65536];
  const int tid = threadIdx.x;
  for (int p = tid * 16; p < 65536; p += 4096)
    *(float4*)(ldsc + p) = *(const float4*)((const char*)Wt + p);
  __syncthreads();
  const int wv = tid >> 6, lane = tid & 63, quad = lane >> 4, l16 = lane & 15;
  bf16x8 breg[CTW][KF];
#pragma unroll
  for (int ct = 0; ct < CTW; ++ct) {
    const int col = wv * 32 + ct * 16 + l16;
#pragma unroll
    for (int f = 0; f < KF; ++f)
      breg[ct][f] = *(const bf16x8*)(ldsc + col * 512 + f * 64 + quad * 16);
  }
  __syncthreads();

  const float a2 = 1.0f + eps2p[0];
  const int hi = lane >> 5;    // row parity within pair
  const int c32 = lane & 31;   // 16B chunk index in row
  const int ntiles = (R + 63) >> 6;
  float4 ereg[8];
  bf16x4 lreg[8];
  auto loadRegs = [&](int t) {
#pragma unroll
    for (int it = 0; it < 8; ++it) {
      int g = t * 64 + wv * 16 + it * 2 + hi;
      if (g > R - 1) g = R - 1;
      ereg[it] = *(const float4*)(edge + (size_t)g * 128 + c32 * 4);
      // fused gather1: segment-sum node rows for edge g (node is L3-hot)
      const int b0 = off_e[g], en = off_e[g + 1];
      float4 a = make_float4(0.f, 0.f, 0.f, 0.f);
      for (int j = b0; j < en; ++j) {
        const int r = csr_e[j];
        float4 v = *(const float4*)(node + (size_t)r * 128 + c32 * 4);
        a.x += v.x; a.y += v.y; a.z += v.z; a.w += v.w;
      }
      bf16x4 lv;
      lv[0] = (bf16_t)a.x; lv[1] = (bf16_t)a.y;
      lv[2] = (bf16_t)a.z; lv[3] = (bf16_t)a.w;
      lreg[it] = lv;
    }
  };
  auto stageHe = [&](int t, int b) {
    char* db = ldsc + b * 32768;
#pragma unroll
    for (int it = 0; it < 8; ++it) {
      const int rl = wv * 16 + it * 2 + hi;
      const int g = t * 64 + rl;
      const float4 e = ereg[it];
      const bf16x4 lv = lreg[it];
      bf16x4 ev, hv;
      ev[0] = (bf16_t)e.x; ev[1] = (bf16_t)e.y;
      ev[2] = (bf16_t)e.z; ev[3] = (bf16_t)e.w;
      hv[0] = (bf16_t)fmaf(a2, e.x, (float)lv[0]);
      hv[1] = (bf16_t)fmaf(a2, e.y, (float)lv[1]);
      hv[2] = (bf16_t)fmaf(a2, e.z, (float)lv[2]);
      hv[3] = (bf16_t)fmaf(a2, e.w, (float)lv[3]);
      if (g < R) *(bf16x4*)(he + (size_t)g * 128 + c32 * 4) = hv;
      const int half = (c32 & 1) * 8;
      const int swl = (((c32 >> 1)) ^ (rl & 7)) * 16 + half;        // lift
      const int swe = (((c32 >> 1) + 16) ^ (rl & 7)) * 16 + half;   // edge
      *(bf16x4*)(db + rl * 512 + swl) = lv;
      *(bf16x4*)(db + rl * 512 + swe) = ev;
    }
  };

  float csum[CTW] = {0.f, 0.f}, csq[CTW] = {0.f, 0.f};
  int t = blockIdx.x, b = 0;
  if (t < ntiles) {
    loadRegs(t);
    stageHe(t, 0);
  }
  __syncthreads();
  for (; t < ntiles; t += gridDim.x) {
    const int tn = t + gridDim.x;
    if (tn < ntiles) loadRegs(tn);  // gather for next tile hides under MFMA
    const char* Ab = ldsc + b * 32768;
    f32x4 acc[4][CTW] = {};
#pragma unroll
    for (int f = 0; f < KF; ++f) {
      const int csw = ((f * 4 + quad) ^ (l16 & 7)) * 16;
#pragma unroll
      for (int rg = 0; rg < 4; ++rg) {
        bf16x8 a = *(const bf16x8*)(Ab + (rg * 16 + l16) * 512 + csw);
#pragma unroll
        for (int ct = 0; ct < CTW; ++ct)
          acc[rg][ct] = __builtin_amdgcn_mfma_f32_16x16x32_bf16(
              a, breg[ct][f], acc[rg][ct], 0, 0, 0);
      }
    }
#pragma unroll
    for (int rg = 0; rg < 4; ++rg) {
      const int rowb = t * 64 + rg * 16 + quad * 4;
#pragma unroll
      for (int ct = 0; ct < CTW; ++ct) {
        const int col = wv * 32 + ct * 16 + l16;
#pragma unroll
        for (int r = 0; r < 4; ++r) {
          const int row = rowb + r;
          if (row < R) {
            const float v = acc[rg][ct][r];
            Y[(size_t)row * 128 + col] = (bf16_t)v;
            csum[ct] += v;
            csq[ct] += v * v;
          }
        }
      }
    }
    if (tn < ntiles) stageHe(tn, b ^ 1);
    __syncthreads();
    b ^= 1;
  }
#pragma unroll
  for (int ct = 0; ct < CTW; ++ct) {
    float s = csum[ct], q = csq[ct];
    s += __shfl_xor(s, 16, 64);
    s += __shfl_xor(s, 32, 64);
    q += __shfl_xor(q, 16, 64);
    q += __shfl_xor(q, 32, 64);
    if (quad == 0) {
      const int col = wv * 32 + ct * 16 + l16;
      atomAddF(gstats + col, s);
      atomAddF(gstats + 128 + col, q);
    }
  }
}

// ============================ launch ========================================

extern "C" void kernel_launch(void* const* d_in, const int* in_sizes, int n_in,
                              void* d_out, int out_size, void* d_ws,
                              size_t ws_size, hipStream_t stream) {
  const float* node_rep = (const float*)d_in[0];
  const float* edge_rep = (const float*)d_in[1];
  const int* n2e = (const int*)d_in[2];
  const float* Wa = (const float*)d_in[3];
  const float* ga = (const float*)d_in[4];
  const float* ba = (const float*)d_in[5];
  const float* Wb1 = (const float*)d_in[6];
  const float* gb1 = (const float*)d_in[7];
  const float* bb1 = (const float*)d_in[8];
  const float* Wb2 = (const float*)d_in[9];
  const float* gb2 = (const float*)d_in[10];
  const float* bb2 = (const float*)d_in[11];
  const float* Wl1 = (const float*)d_in[12];
  const float* gl1 = (const float*)d_in[13];
  const float* bl1 = (const float*)d_in[14];
  const float* Wl2 = (const float*)d_in[15];
  const float* gl2 = (const float*)d_in[16];
  const float* bl2 = (const float*)d_in[17];
  const float* eps1 = (const float*)d_in[18];
  const float* eps2 = (const float*)d_in[19];

  const int N = in_sizes[0] / 128;
  const int E = in_sizes[1] / 128;
  const int M = in_sizes[2] / 2;
  const int* srcI = n2e;
  const int* dstI = n2e + M;

  char* wsb = (char*)d_ws;
  size_t off = 0;
  auto alloc = [&](size_t bytes) {
    void* p = wsb + off;
    off += (bytes + 255) & ~(size_t)255;
    return p;
  };
  // region1: two E*128 halves (Ze overlays both; Zn/Y2n overlay later)
  bf16_t* r1a  = (bf16_t*)alloc((size_t)E * 128 * 2);
  bf16_t* Y1   = (bf16_t*)alloc((size_t)E * 128 * 2);
  // region2
  bf16_t* he   = (bf16_t*)alloc((size_t)E * 128 * 2);
  bf16_t* hn   = (bf16_t*)alloc((size_t)N * 128 * 2);
  bf16_t* Wa_t  = (bf16_t*)alloc(256 * 128 * 2);
  bf16_t* Wb1_t = (bf16_t*)alloc(128 * 256 * 2);
  bf16_t* Wb2_t = (bf16_t*)alloc(256 * 128 * 2);
  bf16_t* Wl1_t = (bf16_t*)alloc(128 * 256 * 2);
  bf16_t* Wl2_t = (bf16_t*)alloc(256 * 128 * 2);
  int* zbase  = (int*)alloc(((size_t)E * 2 + (size_t)N * 2 + 8192) * 4);
  int* cnt_e  = zbase;
  int* fill_e = zbase + E;
  int* cnt_n  = zbase + 2 * (size_t)E;
  int* fill_n = zbase + 2 * (size_t)E + N;
  float* stats = (float*)(zbase + 2 * (size_t)E + 2 * (size_t)N);
  int* off_e  = (int*)alloc((size_t)(E + 1) * 4);
  int* csr_e  = (int*)alloc((size_t)M * 4);
  int* off_n  = (int*)alloc((size_t)(N + 1) * 4);
  int* csr_n  = (int*)alloc((size_t)M * 4);
  int* bsumE  = (int*)alloc(4096 * 4);
  int* bsumN  = (int*)alloc(4096 * 4);

  // aliases over dead regions (edge path before node path)
  bf16_t* Ze  = r1a;   // E*256*2 spans r1a+Y1 (both dead when written)
  bf16_t* Y2e = he;    // he dead after edge-W1
  bf16_t* Zn  = r1a;   // Ze dead after edge-W2
  bf16_t* Y2n = Y1;    // disjoint from Zn (N*256*2 < E*128*2)

  float* sum_a  = stats + 0;
  float* st_a   = stats + 256;
  float* sum_b1 = stats + 512;
  float* st_b1  = stats + 1024;
  float* sum_b2 = stats + 1536;
  float* st_b2  = stats + 1792;
  float* sum_l1 = stats + 2048;
  float* st_l1  = stats + 2560;
  float* sum_l2 = stats + 3072;
  float* st_l2  = stats + 3328;

  float* node_out = (float*)d_out;
  float* edge_out = (float*)d_out + (size_t)N * 128;

  hipMemsetAsync(zbase, 0, ((size_t)E * 2 + (size_t)N * 2 + 8192) * 4, stream);

  // ---- CSR build ----
  k_hist<<<(M + 255) / 256, 256, 0, stream>>>(srcI, dstI, M, cnt_e, cnt_n);
  const int nbE = (E + 1023) / 1024;
  const int nbN = (N + 1023) / 1024;
  k_scan_block<<<nbE, 256, 0, stream>>>(cnt_e, off_e, bsumE, E);
  k_scan_top<<<1, 1024, 0, stream>>>(bsumE, nbE);
  k_scan_add<<<nbE, 256, 0, stream>>>(off_e, bsumE, E);
  k_scan_block<<<nbN, 256, 0, stream>>>(cnt_n, off_n, bsumN, N);
  k_scan_top<<<1, 1024, 0, stream>>>(bsumN, nbN);
  k_scan_add<<<nbN, 256, 0, stream>>>(off_n, bsumN, N);
  k_settail<<<1, 1, 0, stream>>>(off_e, E, off_n, N, M);
  k_fill<<<(M + 255) / 256, 256, 0, stream>>>(srcI, dstI, M, off_e, fill_e,
                                              csr_e, off_n, fill_n, csr_n);

  // ---- weight conversion ----
  k_wconv<<<128, 256, 0, stream>>>(Wa, Wa_t, 256, 128);
  k_wconv<<<128, 256, 0, stream>>>(Wb1, Wb1_t, 128, 256);
  k_wconv<<<128, 256, 0, stream>>>(Wb2, Wb2_t, 256, 128);
  k_wconv<<<128, 256, 0, stream>>>(Wl1, Wl1_t, 128, 256);
  k_wconv<<<128, 256, 0, stream>>>(Wl2, Wl2_t, 256, 128);

  const int ntE = (E + 63) / 64, gE = ntE < 512 ? ntE : 512;
  const int ntN = (N + 63) / 64, gN = ntN < 512 ? ntN : 512;

  // 1) fused gather1 + Y1 = [lift|edge] @ Wa (+stats, +he)
  k_gemm_cat_rb<<<gE, 256, 0, stream>>>(node_rep, off_e, csr_e, edge_rep,
                                        Wa_t, eps2, sum_a, Y1, he, E);
  k_bnfin<<<1, 256, 0, stream>>>(sum_a, 128, E, ga, ba, st_a);

  // 2) gather2: lvl + hn  (last reader of Y1)
  k_gather2<<<(N + 15) / 16, 256, 0, stream>>>(Y1, st_a, node_rep, off_n,
                                               csr_n, eps1, hn, N);

  // 3) EDGE path (Ze overlays dead region1)
  k_gemm_rb<128, 256, 0><<<gE, 256, 0, stream>>>(he, Wl1_t, nullptr, sum_l1,
                                                 Ze, E);
  k_bnfin<<<1, 256, 0, stream>>>(sum_l1, 256, E, gl1, bl1, st_l1);
  k_gemm_rb<256, 128, 1><<<gE, 256, 0, stream>>>(Ze, Wl2_t, st_l1, sum_l2,
                                                 Y2e, E);
  k_bnfin<<<1, 256, 0, stream>>>(sum_l2, 128, E, gl2, bl2, st_l2);
  {
    long total = ((long)E * 128 + 7) / 8;
    k_bnrelu_out<<<(int)((total + 255) / 256), 256, 0, stream>>>(Y2e, st_l2, E,
                                                                 edge_out);
  }

  // 4) NODE path (Zn/Y2n overlay dead edge regions)
  k_gemm_rb<128, 256, 0><<<gN, 256, 0, stream>>>(hn, Wb1_t, nullptr, sum_b1,
                                                 Zn, N);
  k_bnfin<<<1, 256, 0, stream>>>(sum_b1, 256, N, gb1, bb1, st_b1);
  k_gemm_rb<256, 128, 1><<<gN, 256, 0, stream>>>(Zn, Wb2_t, st_b1, sum_b2,
                                                 Y2n, N);
  k_bnfin<<<1, 256, 0, stream>>>(sum_b2, 128, N, gb2, bb2, st_b2);
  {
    long total = ((long)N * 128 + 7) / 8;
    k_bnrelu_out<<<(int)((total + 255) / 256), 256, 0, stream>>>(Y2n, st_b2, N,
                                                                 node_out);
  }
}

// Round 15
// 1122.827 us; speedup vs baseline: 1.1219x; 1.1219x over previous
//
#include <hip/hip_runtime.h>
#include <cstdint>
#include <cstddef>

// ---------------------------------------------------------------------------
// SplitLayer. FINAL: round-6 configuration verbatim (best measured: 1139us).
// Session ledger: coalesced gload_lds streaming + reg-resident B (this) beat
// swapped-MFMA scatter stores (r7), LDS-transpose epilogue (r8), barrier-free
// wave-decoupled (r9), aliasing reorder (r10, neutral), gather fusion (r11,
// regressed). GEMMs sit at ~1.7TB/s effective with all pipes <35%; no
// remaining unfalsified hypothesis predicts >5%.
// ---------------------------------------------------------------------------

typedef __bf16 bf16_t;
typedef __bf16 bf16x4 __attribute__((ext_vector_type(4)));
typedef __bf16 bf16x8 __attribute__((ext_vector_type(8)));
typedef float f32x4 __attribute__((ext_vector_type(4)));

__device__ __forceinline__ void atomAddF(float* p, float v) {
  unsafeAtomicAdd(p, v);
}

__device__ __forceinline__ void gload16(const void* g, void* l) {
  __builtin_amdgcn_global_load_lds(
      (const __attribute__((address_space(1))) unsigned int*)g,
      (__attribute__((address_space(3))) unsigned int*)l, 16, 0, 0);
}

// ============================ CSR construction ==============================

__global__ __launch_bounds__(256) void k_hist(
    const int* __restrict__ src, const int* __restrict__ dst, int M,
    int* __restrict__ cnt_e, int* __restrict__ cnt_n) {
  int i = blockIdx.x * blockDim.x + threadIdx.x;
  if (i >= M) return;
  atomicAdd(cnt_e + dst[i], 1);
  atomicAdd(cnt_n + src[i], 1);
}

__global__ __launch_bounds__(256) void k_scan_block(
    const int* __restrict__ in, int* __restrict__ out, int* __restrict__ bsum,
    int L) {
  __shared__ int sh[256];
  int t = threadIdx.x;
  int base = (blockIdx.x * 256 + t) * 4;
  int v[4];
#pragma unroll
  for (int j = 0; j < 4; ++j) v[j] = (base + j < L) ? in[base + j] : 0;
  int tsum = v[0] + v[1] + v[2] + v[3];
  sh[t] = tsum;
  __syncthreads();
#pragma unroll
  for (int off = 1; off < 256; off <<= 1) {
    int x = (t >= off) ? sh[t - off] : 0;
    __syncthreads();
    sh[t] += x;
    __syncthreads();
  }
  int excl = sh[t] - tsum;
  if (t == 255) bsum[blockIdx.x] = sh[255];
  int run = excl;
#pragma unroll
  for (int j = 0; j < 4; ++j) {
    if (base + j < L) out[base + j] = run;
    run += v[j];
  }
}

__global__ __launch_bounds__(1024) void k_scan_top(int* __restrict__ bsum,
                                                   int nb) {
  __shared__ int sh[1024];
  __shared__ int running;
  int t = threadIdx.x;
  if (t == 0) running = 0;
  __syncthreads();
  for (int c = 0; c < nb; c += 1024) {
    int i = c + t;
    int v = (i < nb) ? bsum[i] : 0;
    sh[t] = v;
    __syncthreads();
#pragma unroll
    for (int off = 1; off < 1024; off <<= 1) {
      int x = (t >= off) ? sh[t - off] : 0;
      __syncthreads();
      sh[t] += x;
      __syncthreads();
    }
    int r = running;
    if (i < nb) bsum[i] = r + sh[t] - v;
    __syncthreads();
    if (t == 1023) running = r + sh[1023];
    __syncthreads();
  }
}

__global__ __launch_bounds__(256) void k_scan_add(int* __restrict__ out,
                                                  const int* __restrict__ bsum,
                                                  int L) {
  int base = (blockIdx.x * 256 + threadIdx.x) * 4;
  int add = bsum[blockIdx.x];
#pragma unroll
  for (int j = 0; j < 4; ++j)
    if (base + j < L) out[base + j] += add;
}

__global__ void k_settail(int* off_e, int E, int* off_n, int N, int M) {
  off_e[E] = M;
  off_n[N] = M;
}

__global__ __launch_bounds__(256) void k_fill(
    const int* __restrict__ src, const int* __restrict__ dst, int M,
    const int* __restrict__ off_e, int* __restrict__ fill_e,
    int* __restrict__ csr_e, const int* __restrict__ off_n,
    int* __restrict__ fill_n, int* __restrict__ csr_n) {
  int i = blockIdx.x * blockDim.x + threadIdx.x;
  if (i >= M) return;
  int s = src[i], d = dst[i];
  int pe = off_e[d] + atomicAdd(fill_e + d, 1);
  csr_e[pe] = s;
  int pn = off_n[s] + atomicAdd(fill_n + s, 1);
  csr_n[pn] = d;
}

// ============================ weight transpose+convert ======================
__global__ __launch_bounds__(256) void k_wconv(const float* __restrict__ W,
                                               bf16_t* __restrict__ Wt, int K,
                                               int NC) {
  int idx = blockIdx.x * blockDim.x + threadIdx.x;
  if (idx >= K * NC) return;
  int k = idx / NC, n = idx % NC;
  Wt[(size_t)n * K + k] = (bf16_t)W[idx];
}

// ============================ gather1: lift only ============================
__global__ __launch_bounds__(256) void k_gather1(
    const float* __restrict__ node, const int* __restrict__ off_e,
    const int* __restrict__ csr_e, bf16_t* __restrict__ lift, int E) {
  int e = blockIdx.x * 8 + (threadIdx.x >> 5);
  if (e >= E) return;
  int l = threadIdx.x & 31;
  int b = off_e[e], en = off_e[e + 1];
  float4 acc = make_float4(0.f, 0.f, 0.f, 0.f);
  for (int j = b; j < en; ++j) {
    int r = csr_e[j];
    float4 v = *(const float4*)(node + (size_t)r * 128 + l * 4);
    acc.x += v.x; acc.y += v.y; acc.z += v.z; acc.w += v.w;
  }
  bf16x4 o;
  o[0] = (bf16_t)acc.x; o[1] = (bf16_t)acc.y;
  o[2] = (bf16_t)acc.z; o[3] = (bf16_t)acc.w;
  *(bf16x4*)(lift + (size_t)e * 128 + l * 4) = o;
}

// ============================ gather2: lvl + hn =============================
__global__ __launch_bounds__(256) void k_gather2(
    const bf16_t* __restrict__ Y1, const float* __restrict__ st,
    const float* __restrict__ node, const int* __restrict__ off_n,
    const int* __restrict__ csr_n, const float* __restrict__ eps1p,
    bf16_t* __restrict__ hn, int N) {
  int n = blockIdx.x * 16 + (threadIdx.x >> 4);
  if (n >= N) return;
  int l = threadIdx.x & 15;
  float a1 = 1.0f + eps1p[0];
  float4 s0 = *(const float4*)(st + l * 8);
  float4 s1 = *(const float4*)(st + l * 8 + 4);
  float4 t0 = *(const float4*)(st + 128 + l * 8);
  float4 t1 = *(const float4*)(st + 128 + l * 8 + 4);
  float acc[8] = {0.f, 0.f, 0.f, 0.f, 0.f, 0.f, 0.f, 0.f};
  int b = off_n[n], en = off_n[n + 1];
  for (int j = b; j < en; ++j) {
    int r = csr_n[j];
    bf16x8 y = *(const bf16x8*)(Y1 + (size_t)r * 128 + l * 8);
    acc[0] += fmaxf(fmaf((float)y[0], s0.x, t0.x), 0.f);
    acc[1] += fmaxf(fmaf((float)y[1], s0.y, t0.y), 0.f);
    acc[2] += fmaxf(fmaf((float)y[2], s0.z, t0.z), 0.f);
    acc[3] += fmaxf(fmaf((float)y[3], s0.w, t0.w), 0.f);
    acc[4] += fmaxf(fmaf((float)y[4], s1.x, t1.x), 0.f);
    acc[5] += fmaxf(fmaf((float)y[5], s1.y, t1.y), 0.f);
    acc[6] += fmaxf(fmaf((float)y[6], s1.z, t1.z), 0.f);
    acc[7] += fmaxf(fmaf((float)y[7], s1.w, t1.w), 0.f);
  }
  float4 n0 = *(const float4*)(node + (size_t)n * 128 + l * 8);
  float4 n1 = *(const float4*)(node + (size_t)n * 128 + l * 8 + 4);
  bf16x8 hb;
  hb[0] = (bf16_t)fmaf(a1, n0.x, acc[0]);
  hb[1] = (bf16_t)fmaf(a1, n0.y, acc[1]);
  hb[2] = (bf16_t)fmaf(a1, n0.z, acc[2]);
  hb[3] = (bf16_t)fmaf(a1, n0.w, acc[3]);
  hb[4] = (bf16_t)fmaf(a1, n1.x, acc[4]);
  hb[5] = (bf16_t)fmaf(a1, n1.y, acc[5]);
  hb[6] = (bf16_t)fmaf(a1, n1.z, acc[6]);
  hb[7] = (bf16_t)fmaf(a1, n1.w, acc[7]);
  *(bf16x8*)(hn + (size_t)n * 128 + l * 8) = hb;
}

// ============================ BN finalize / output ==========================

__global__ void k_bnfin(const float* __restrict__ sums, int C, int R,
                        const float* __restrict__ g, const float* __restrict__ b,
                        float* __restrict__ st) {
  int c = blockIdx.x * blockDim.x + threadIdx.x;
  if (c >= C) return;
  float invR = 1.f / (float)R;
  float mean = sums[c] * invR;
  float var = fmaxf(sums[C + c] * invR - mean * mean, 0.f);
  float s = g[c] * rsqrtf(var + 1e-5f);
  st[c] = s;
  st[C + c] = fmaf(-mean, s, b[c]);
}

__global__ __launch_bounds__(256) void k_bnrelu_out(
    const bf16_t* __restrict__ Y, const float* __restrict__ st, long R,
    float* __restrict__ out) {
  long t = (long)blockIdx.x * blockDim.x + threadIdx.x;
  long idx = t * 8;
  if (idx >= R * 128) return;
  int c = (int)(idx & 127);
  bf16x8 y = *(const bf16x8*)(Y + idx);
  float4 s0 = *(const float4*)(st + c);
  float4 s1 = *(const float4*)(st + c + 4);
  float4 t0 = *(const float4*)(st + 128 + c);
  float4 t1 = *(const float4*)(st + 128 + c + 4);
  float4 o0, o1;
  o0.x = fmaxf(fmaf((float)y[0], s0.x, t0.x), 0.f);
  o0.y = fmaxf(fmaf((float)y[1], s0.y, t0.y), 0.f);
  o0.z = fmaxf(fmaf((float)y[2], s0.z, t0.z), 0.f);
  o0.w = fmaxf(fmaf((float)y[3], s0.w, t0.w), 0.f);
  o1.x = fmaxf(fmaf((float)y[4], s1.x, t1.x), 0.f);
  o1.y = fmaxf(fmaf((float)y[5], s1.y, t1.y), 0.f);
  o1.z = fmaxf(fmaf((float)y[6], s1.z, t1.z), 0.f);
  o1.w = fmaxf(fmaf((float)y[7], s1.w, t1.w), 0.f);
  *(float4*)(out + idx) = o0;
  *(float4*)(out + idx + 4) = o1;
}

// =================== reg-resident-B, LDS-streamed-A GEMM ====================
template <int K, int NC, int TRANSFORM>
__global__ __launch_bounds__(256, 2) void k_gemm_rb(
    const bf16_t* __restrict__ A, const bf16_t* __restrict__ Wt,
    const float* __restrict__ st, float* __restrict__ gstats,
    bf16_t* __restrict__ Y, int R) {
  constexpr int K2 = K * 2;       // A row bytes
  constexpr int KF = K / 32;      // k-steps per tile
  constexpr int CTW = NC / 64;    // col-tiles per wave
  constexpr int STG = K2 / 64;    // gload_lds insts per wave per tile
  constexpr int TILEB = 64 * K2;  // A-tile bytes (16/32 KB)
  __shared__ __align__(16) char ldsc[65536];
  const int tid = threadIdx.x;

  // ---- stage whole B (64 KB) once, hoist this wave's fragments to regs ----
  for (int p = tid * 16; p < 65536; p += 4096)
    *(float4*)(ldsc + p) = *(const float4*)((const char*)Wt + p);
  __syncthreads();
  const int wv = tid >> 6, lane = tid & 63, quad = lane >> 4, l16 = lane & 15;
  bf16x8 breg[CTW][KF];
#pragma unroll
  for (int ct = 0; ct < CTW; ++ct) {
    const int col = wv * (NC / 4) + ct * 16 + l16;
#pragma unroll
    for (int f = 0; f < KF; ++f)
      breg[ct][f] = *(const bf16x8*)(ldsc + col * K2 + f * 64 + quad * 16);
  }
  __syncthreads();  // B in regs; LDS becomes the A double-buffer

  // per-lane staging map: LDS p = j*1024 + lane*16 <- global (row, c^row&7)
  int stg_off[STG], stg_row[STG];
#pragma unroll
  for (int j = 0; j < STG; ++j) {
    const int p = j * 1024 + lane * 16;
    const int rl = p / K2;
    const int cg = ((p & (K2 - 1)) >> 4) ^ (rl & 7);
    stg_row[j] = rl;
    stg_off[j] = rl * K2 + cg * 16;
  }
  const int ntiles = (R + 63) >> 6;
  auto stage = [&](int t, int b) {
    char* db = ldsc + b * TILEB + wv * (16 * K2);
    if (t * 64 + 64 <= R) {
      const char* srcb = (const char*)A + (size_t)(t * 64 + wv * 16) * K2;
#pragma unroll
      for (int j = 0; j < STG; ++j) gload16(srcb + stg_off[j], db + j * 1024);
    } else {
#pragma unroll
      for (int j = 0; j < STG; ++j) {
        int g = t * 64 + wv * 16 + stg_row[j];
        if (g > R - 1) g = R - 1;
        gload16((const char*)A + (size_t)g * K2 +
                    (stg_off[j] - stg_row[j] * K2),
                db + j * 1024);
      }
    }
  };

  float csum[CTW], csq[CTW];
#pragma unroll
  for (int ct = 0; ct < CTW; ++ct) { csum[ct] = 0.f; csq[ct] = 0.f; }

  int t = blockIdx.x, b = 0;
  if (t < ntiles) stage(t, 0);
  __syncthreads();
  for (; t < ntiles; t += gridDim.x) {
    const int tn = t + gridDim.x;
    if (tn < ntiles) stage(tn, b ^ 1);  // async; drained by end barrier
    const char* Ab = ldsc + b * TILEB;
    f32x4 acc[4][CTW] = {};
#pragma unroll
    for (int f = 0; f < KF; ++f) {
      const int csw = ((f * 4 + quad) ^ (l16 & 7)) * 16;
      float4 s0, s1, u0, u1;
      if constexpr (TRANSFORM != 0) {
        const int k = f * 32 + quad * 8;
        s0 = *(const float4*)(st + k);
        s1 = *(const float4*)(st + k + 4);
        u0 = *(const float4*)(st + K + k);
        u1 = *(const float4*)(st + K + k + 4);
      }
#pragma unroll
      for (int rg = 0; rg < 4; ++rg) {
        bf16x8 a = *(const bf16x8*)(Ab + (rg * 16 + l16) * K2 + csw);
        if constexpr (TRANSFORM != 0) {
          bf16x8 o;
          o[0] = (bf16_t)fmaxf(fmaf((float)a[0], s0.x, u0.x), 0.f);
          o[1] = (bf16_t)fmaxf(fmaf((float)a[1], s0.y, u0.y), 0.f);
          o[2] = (bf16_t)fmaxf(fmaf((float)a[2], s0.z, u0.z), 0.f);
          o[3] = (bf16_t)fmaxf(fmaf((float)a[3], s0.w, u0.w), 0.f);
          o[4] = (bf16_t)fmaxf(fmaf((float)a[4], s1.x, u1.x), 0.f);
          o[5] = (bf16_t)fmaxf(fmaf((float)a[5], s1.y, u1.y), 0.f);
          o[6] = (bf16_t)fmaxf(fmaf((float)a[6], s1.z, u1.z), 0.f);
          o[7] = (bf16_t)fmaxf(fmaf((float)a[7], s1.w, u1.w), 0.f);
          a = o;
        }
#pragma unroll
        for (int ct = 0; ct < CTW; ++ct)
          acc[rg][ct] = __builtin_amdgcn_mfma_f32_16x16x32_bf16(
              a, breg[ct][f], acc[rg][ct], 0, 0, 0);
      }
    }
#pragma unroll
    for (int rg = 0; rg < 4; ++rg) {
      const int rowb = t * 64 + rg * 16 + quad * 4;
#pragma unroll
      for (int ct = 0; ct < CTW; ++ct) {
        const int col = wv * (NC / 4) + ct * 16 + l16;
#pragma unroll
        for (int r = 0; r < 4; ++r) {
          const int row = rowb + r;
          if (row < R) {
            const float v = acc[rg][ct][r];
            Y[(size_t)row * NC + col] = (bf16_t)v;
            csum[ct] += v;
            csq[ct] += v * v;
          }
        }
      }
    }
    __syncthreads();
    b ^= 1;
  }
#pragma unroll
  for (int ct = 0; ct < CTW; ++ct) {
    float s = csum[ct], q = csq[ct];
    s += __shfl_xor(s, 16, 64);
    s += __shfl_xor(s, 32, 64);
    q += __shfl_xor(q, 16, 64);
    q += __shfl_xor(q, 32, 64);
    if (quad == 0) {
      const int col = wv * (NC / 4) + ct * 16 + l16;
      atomAddF(gstats + col, s);
      atomAddF(gstats + NC + col, q);
    }
  }
}

// ============ concat GEMM-1: A=[lift bf16 | edge f32], emits he =============
__global__ __launch_bounds__(256, 2) void k_gemm_cat_rb(
    const bf16_t* __restrict__ lift, const float* __restrict__ edge,
    const bf16_t* __restrict__ Wt, const float* __restrict__ eps2p,
    float* __restrict__ gstats, bf16_t* __restrict__ Y,
    bf16_t* __restrict__ he, int R) {
  constexpr int KF = 8, CTW = 2;
  __shared__ __align__(16) char ldsc[65536];
  const int tid = threadIdx.x;
  for (int p = tid * 16; p < 65536; p += 4096)
    *(float4*)(ldsc + p) = *(const float4*)((const char*)Wt + p);
  __syncthreads();
  const int wv = tid >> 6, lane = tid & 63, quad = lane >> 4, l16 = lane & 15;
  bf16x8 breg[CTW][KF];
#pragma unroll
  for (int ct = 0; ct < CTW; ++ct) {
    const int col = wv * 32 + ct * 16 + l16;
#pragma unroll
    for (int f = 0; f < KF; ++f)
      breg[ct][f] = *(const bf16x8*)(ldsc + col * 512 + f * 64 + quad * 16);
  }
  __syncthreads();

  const float a2 = 1.0f + eps2p[0];
  const int hi = lane >> 5;    // row parity within pair
  const int c32 = lane & 31;   // f32 16B-chunk index in row
  const int ntiles = (R + 63) >> 6;
  float4 ereg[8];
  bf16x4 lreg[8];
  auto loadRegs = [&](int t) {
#pragma unroll
    for (int it = 0; it < 8; ++it) {
      int g = t * 64 + wv * 16 + it * 2 + hi;
      if (g > R - 1) g = R - 1;
      ereg[it] = *(const float4*)(edge + (size_t)g * 128 + c32 * 4);
      lreg[it] = *(const bf16x4*)(lift + (size_t)g * 128 + c32 * 4);
    }
  };
  auto stageHe = [&](int t, int b) {
    char* db = ldsc + b * 32768;
#pragma unroll
    for (int it = 0; it < 8; ++it) {
      const int rl = wv * 16 + it * 2 + hi;
      const int g = t * 64 + rl;
      const float4 e = ereg[it];
      const bf16x4 lv = lreg[it];
      bf16x4 ev, hv;
      ev[0] = (bf16_t)e.x; ev[1] = (bf16_t)e.y;
      ev[2] = (bf16_t)e.z; ev[3] = (bf16_t)e.w;
      hv[0] = (bf16_t)fmaf(a2, e.x, (float)lv[0]);
      hv[1] = (bf16_t)fmaf(a2, e.y, (float)lv[1]);
      hv[2] = (bf16_t)fmaf(a2, e.z, (float)lv[2]);
      hv[3] = (bf16_t)fmaf(a2, e.w, (float)lv[3]);
      if (g < R) *(bf16x4*)(he + (size_t)g * 128 + c32 * 4) = hv;
      const int half = (c32 & 1) * 8;
      const int swl = (((c32 >> 1)) ^ (rl & 7)) * 16 + half;        // lift
      const int swe = (((c32 >> 1) + 16) ^ (rl & 7)) * 16 + half;   // edge
      *(bf16x4*)(db + rl * 512 + swl) = lv;
      *(bf16x4*)(db + rl * 512 + swe) = ev;
    }
  };

  float csum[CTW] = {0.f, 0.f}, csq[CTW] = {0.f, 0.f};
  int t = blockIdx.x, b = 0;
  if (t < ntiles) {
    loadRegs(t);
    stageHe(t, 0);
  }
  __syncthreads();
  for (; t < ntiles; t += gridDim.x) {
    const int tn = t + gridDim.x;
    if (tn < ntiles) loadRegs(tn);  // issue early; waited in stageHe below
    const char* Ab = ldsc + b * 32768;
    f32x4 acc[4][CTW] = {};
#pragma unroll
    for (int f = 0; f < KF; ++f) {
      const int csw = ((f * 4 + quad) ^ (l16 & 7)) * 16;
#pragma unroll
      for (int rg = 0; rg < 4; ++rg) {
        bf16x8 a = *(const bf16x8*)(Ab + (rg * 16 + l16) * 512 + csw);
#pragma unroll
        for (int ct = 0; ct < CTW; ++ct)
          acc[rg][ct] = __builtin_amdgcn_mfma_f32_16x16x32_bf16(
              a, breg[ct][f], acc[rg][ct], 0, 0, 0);
      }
    }
#pragma unroll
    for (int rg = 0; rg < 4; ++rg) {
      const int rowb = t * 64 + rg * 16 + quad * 4;
#pragma unroll
      for (int ct = 0; ct < CTW; ++ct) {
        const int col = wv * 32 + ct * 16 + l16;
#pragma unroll
        for (int r = 0; r < 4; ++r) {
          const int row = rowb + r;
          if (row < R) {
            const float v = acc[rg][ct][r];
            Y[(size_t)row * 128 + col] = (bf16_t)v;
            csum[ct] += v;
            csq[ct] += v * v;
          }
        }
      }
    }
    if (tn < ntiles) stageHe(tn, b ^ 1);
    __syncthreads();
    b ^= 1;
  }
#pragma unroll
  for (int ct = 0; ct < CTW; ++ct) {
    float s = csum[ct], q = csq[ct];
    s += __shfl_xor(s, 16, 64);
    s += __shfl_xor(s, 32, 64);
    q += __shfl_xor(q, 16, 64);
    q += __shfl_xor(q, 32, 64);
    if (quad == 0) {
      const int col = wv * 32 + ct * 16 + l16;
      atomAddF(gstats + col, s);
      atomAddF(gstats + 128 + col, q);
    }
  }
}

// ============================ launch ========================================

extern "C" void kernel_launch(void* const* d_in, const int* in_sizes, int n_in,
                              void* d_out, int out_size, void* d_ws,
                              size_t ws_size, hipStream_t stream) {
  const float* node_rep = (const float*)d_in[0];
  const float* edge_rep = (const float*)d_in[1];
  const int* n2e = (const int*)d_in[2];
  const float* Wa = (const float*)d_in[3];
  const float* ga = (const float*)d_in[4];
  const float* ba = (const float*)d_in[5];
  const float* Wb1 = (const float*)d_in[6];
  const float* gb1 = (const float*)d_in[7];
  const float* bb1 = (const float*)d_in[8];
  const float* Wb2 = (const float*)d_in[9];
  const float* gb2 = (const float*)d_in[10];
  const float* bb2 = (const float*)d_in[11];
  const float* Wl1 = (const float*)d_in[12];
  const float* gl1 = (const float*)d_in[13];
  const float* bl1 = (const float*)d_in[14];
  const float* Wl2 = (const float*)d_in[15];
  const float* gl2 = (const float*)d_in[16];
  const float* bl2 = (const float*)d_in[17];
  const float* eps1 = (const float*)d_in[18];
  const float* eps2 = (const float*)d_in[19];

  const int N = in_sizes[0] / 128;
  const int E = in_sizes[1] / 128;
  const int M = in_sizes[2] / 2;
  const int* srcI = n2e;
  const int* dstI = n2e + M;

  char* wsb = (char*)d_ws;
  size_t off = 0;
  auto alloc = [&](size_t bytes) {
    void* p = wsb + off;
    off += (bytes + 255) & ~(size_t)255;
    return p;
  };
  bf16_t* lift = (bf16_t*)alloc((size_t)E * 128 * 2);
  bf16_t* he   = (bf16_t*)alloc((size_t)E * 128 * 2);
  bf16_t* Y1   = (bf16_t*)alloc((size_t)E * 128 * 2);
  bf16_t* Ze   = (bf16_t*)alloc((size_t)E * 256 * 2);
  bf16_t* Y2e  = (bf16_t*)alloc((size_t)E * 128 * 2);
  bf16_t* hn   = (bf16_t*)alloc((size_t)N * 128 * 2);
  bf16_t* Zn   = (bf16_t*)alloc((size_t)N * 256 * 2);
  bf16_t* Y2n  = (bf16_t*)alloc((size_t)N * 128 * 2);
  bf16_t* Wa_t  = (bf16_t*)alloc(256 * 128 * 2);
  bf16_t* Wb1_t = (bf16_t*)alloc(128 * 256 * 2);
  bf16_t* Wb2_t = (bf16_t*)alloc(256 * 128 * 2);
  bf16_t* Wl1_t = (bf16_t*)alloc(128 * 256 * 2);
  bf16_t* Wl2_t = (bf16_t*)alloc(256 * 128 * 2);
  int* zbase  = (int*)alloc(((size_t)E * 2 + (size_t)N * 2 + 8192) * 4);
  int* cnt_e  = zbase;
  int* fill_e = zbase + E;
  int* cnt_n  = zbase + 2 * (size_t)E;
  int* fill_n = zbase + 2 * (size_t)E + N;
  float* stats = (float*)(zbase + 2 * (size_t)E + 2 * (size_t)N);
  int* off_e  = (int*)alloc((size_t)(E + 1) * 4);
  int* csr_e  = (int*)alloc((size_t)M * 4);
  int* off_n  = (int*)alloc((size_t)(N + 1) * 4);
  int* csr_n  = (int*)alloc((size_t)M * 4);
  int* bsumE  = (int*)alloc(4096 * 4);
  int* bsumN  = (int*)alloc(4096 * 4);

  float* sum_a  = stats + 0;
  float* st_a   = stats + 256;
  float* sum_b1 = stats + 512;
  float* st_b1  = stats + 1024;
  float* sum_b2 = stats + 1536;
  float* st_b2  = stats + 1792;
  float* sum_l1 = stats + 2048;
  float* st_l1  = stats + 2560;
  float* sum_l2 = stats + 3072;
  float* st_l2  = stats + 3328;

  float* node_out = (float*)d_out;
  float* edge_out = (float*)d_out + (size_t)N * 128;

  hipMemsetAsync(zbase, 0, ((size_t)E * 2 + (size_t)N * 2 + 8192) * 4, stream);

  // ---- CSR build ----
  k_hist<<<(M + 255) / 256, 256, 0, stream>>>(srcI, dstI, M, cnt_e, cnt_n);
  const int nbE = (E + 1023) / 1024;
  const int nbN = (N + 1023) / 1024;
  k_scan_block<<<nbE, 256, 0, stream>>>(cnt_e, off_e, bsumE, E);
  k_scan_top<<<1, 1024, 0, stream>>>(bsumE, nbE);
  k_scan_add<<<nbE, 256, 0, stream>>>(off_e, bsumE, E);
  k_scan_block<<<nbN, 256, 0, stream>>>(cnt_n, off_n, bsumN, N);
  k_scan_top<<<1, 1024, 0, stream>>>(bsumN, nbN);
  k_scan_add<<<nbN, 256, 0, stream>>>(off_n, bsumN, N);
  k_settail<<<1, 1, 0, stream>>>(off_e, E, off_n, N, M);
  k_fill<<<(M + 255) / 256, 256, 0, stream>>>(srcI, dstI, M, off_e, fill_e,
                                              csr_e, off_n, fill_n, csr_n);

  // ---- weight conversion ----
  k_wconv<<<128, 256, 0, stream>>>(Wa, Wa_t, 256, 128);
  k_wconv<<<128, 256, 0, stream>>>(Wb1, Wb1_t, 128, 256);
  k_wconv<<<128, 256, 0, stream>>>(Wb2, Wb2_t, 256, 128);
  k_wconv<<<128, 256, 0, stream>>>(Wl1, Wl1_t, 128, 256);
  k_wconv<<<128, 256, 0, stream>>>(Wl2, Wl2_t, 256, 128);

  const int ntE = (E + 63) / 64, gE = ntE < 512 ? ntE : 512;
  const int ntN = (N + 63) / 64, gN = ntN < 512 ? ntN : 512;

  // 1) gather1: lift only
  k_gather1<<<(E + 7) / 8, 256, 0, stream>>>(node_rep, off_e, csr_e, lift, E);

  // 2) Y1 = [lift|edge] @ Wa (+stats, +he)
  k_gemm_cat_rb<<<gE, 256, 0, stream>>>(lift, edge_rep, Wa_t, eps2, sum_a, Y1,
                                        he, E);
  k_bnfin<<<1, 256, 0, stream>>>(sum_a, 128, E, ga, ba, st_a);

  // 3) gather2: lvl + hn
  k_gather2<<<(N + 15) / 16, 256, 0, stream>>>(Y1, st_a, node_rep, off_n,
                                               csr_n, eps1, hn, N);

  // 4) node path
  k_gemm_rb<128, 256, 0><<<gN, 256, 0, stream>>>(hn, Wb1_t, nullptr, sum_b1,
                                                 Zn, N);
  k_bnfin<<<1, 256, 0, stream>>>(sum_b1, 256, N, gb1, bb1, st_b1);
  k_gemm_rb<256, 128, 1><<<gN, 256, 0, stream>>>(Zn, Wb2_t, st_b1, sum_b2,
                                                 Y2n, N);
  k_bnfin<<<1, 256, 0, stream>>>(sum_b2, 128, N, gb2, bb2, st_b2);
  {
    long total = ((long)N * 128 + 7) / 8;
    k_bnrelu_out<<<(int)((total + 255) / 256), 256, 0, stream>>>(Y2n, st_b2, N,
                                                                 node_out);
  }

  // 5) edge path
  k_gemm_rb<128, 256, 0><<<gE, 256, 0, stream>>>(he, Wl1_t, nullptr, sum_l1,
                                                 Ze, E);
  k_bnfin<<<1, 256, 0, stream>>>(sum_l1, 256, E, gl1, bl1, st_l1);
  k_gemm_rb<256, 128, 1><<<gE, 256, 0, stream>>>(Ze, Wl2_t, st_l1, sum_l2,
                                                 Y2e, E);
  k_bnfin<<<1, 256, 0, stream>>>(sum_l2, 128, E, gl2, bl2, st_l2);
  {
    long total = ((long)E * 128 + 7) / 8;
    k_bnrelu_out<<<(int)((total + 255) / 256), 256, 0, stream>>>(Y2e, st_l2, E,
                                                                 edge_out);
  }
}